// Round 19
// baseline (385.713 us; speedup 1.0000x reference)
//
#include <hip/hip_runtime.h>
#include <hip/hip_bf16.h>

// GCN: h1 = relu(Â (x W1) + b1); h2 = relu(Â (h1 W2) + b2);
// out = mean_pool(h2, batch) @ Wlin + blin,  Â = D^-1/2 (A+I) D^-1/2
//
// R5/R6: bucketed CSR build, deterministic two-pass, zero global atomics.
// R8/R9 LESSON: sub-dword per-lane global stores defeat L2 write-merge.
// R10/R17/R18 LESSON: gather bound by outstanding-miss slots per lane;
//     R17 half-wave core (dword/lane, 8 loads in flight) is the optimum;
//     8B/lane quarter-wave (R18) broke even. Gather closed at ~50 us/pass.
// R12 LESSON: multi-NODE gather unroll spills. One node context per wave.
// R14 LESSON: same-address atomic chains ~125 ns/link; keep <= ~100.
// R15/R16: replicated pooled accumulators (32x) decouple chains from occupancy.
// R19: revert to R17 gather. CSR build x4 parallelism (ECHUNK 8192->2048,
//     NBLK 196->782 -- was 196 blocks on 256 CUs; colscan widened to 1024
//     threads). h stored bf16 (agg write + gemm2 read halved). reduce_k
//     folded into final_k.

#define NDIM 64
#define NGRAPH 64
#define NREP 32
#define BSHIFT 7                      // 128 nodes per bucket
#define BNODES 128
#define ECHUNK 2048                   // edges per block in bincnt/bscatter (8/thread)

__device__ __forceinline__ unsigned short f32_to_bf16(float f) {
    unsigned int u = __float_as_uint(f);
    unsigned int r = 0x7FFFu + ((u >> 16) & 1u);   // round-to-nearest-even
    return (unsigned short)((u + r) >> 16);
}

// ---- pass 1: per-(block,bucket) edge counts via LDS histogram ----
__global__ void bincnt_k(const int* __restrict__ dst, int* __restrict__ cntmat,
                         int e, int nb) {
    extern __shared__ int hist[];
    int t = threadIdx.x;
    for (int i = t; i < nb; i += 256) hist[i] = 0;
    __syncthreads();
    int base = blockIdx.x * ECHUNK + t;
#pragma unroll
    for (int k = 0; k < 8; ++k) {
        int i = base + k * 256;
        if (i < e) atomicAdd(&hist[dst[i] >> BSHIFT], 1);   // LDS atomic
    }
    __syncthreads();
    long row = (long)blockIdx.x * nb;
    for (int i = t; i < nb; i += 256) cntmat[row + i] = hist[i];
}

// ---- pass 2: per-bucket exclusive scan across blocks (one block per bucket) ----
// 1024 threads: supports nblk <= 1024
__global__ void colscan_k(const int* __restrict__ cntmat, int* __restrict__ basemat,
                          int* __restrict__ bucketTot, int nblk, int nb) {
    __shared__ int s[1024];
    int b = blockIdx.x;
    int t = threadIdx.x;
    int v = (t < nblk) ? cntmat[(long)t * nb + b] : 0;
    s[t] = v;
    __syncthreads();
    for (int off = 1; off < 1024; off <<= 1) {
        int tmp = (t >= off) ? s[t - off] : 0;
        __syncthreads();
        s[t] += tmp;
        __syncthreads();
    }
    if (t < nblk) basemat[(long)t * nb + b] = s[t] - v;   // exclusive within column
    if (t == 1023) bucketTot[b] = s[1023];
}

// ---- pass 3: exclusive scan of bucket totals (single block, nb<=1024) ----
__global__ void bscan_k(const int* __restrict__ bucketTot, int* __restrict__ bucketStart,
                        int* __restrict__ start, int nb, int n, int e) {
    __shared__ int s[1024];
    int t = threadIdx.x;
    int v = (t < nb) ? bucketTot[t] : 0;
    s[t] = v;
    __syncthreads();
    for (int off = 1; off < 1024; off <<= 1) {
        int tmp = (t >= off) ? s[t - off] : 0;
        __syncthreads();
        s[t] += tmp;
        __syncthreads();
    }
    if (t < nb) bucketStart[t + 1] = s[t];
    if (t == 0) { bucketStart[0] = 0; start[n] = e; }   // CSR sentinel
}

// ---- pass 4: scatter packed (dst_local<<25 | src) via block-private LDS cursors ----
__global__ void bscatter_k(const int* __restrict__ src, const int* __restrict__ dst,
                           const int* __restrict__ bucketStart,
                           const int* __restrict__ basemat,
                           unsigned int* __restrict__ ebuf, int e, int nb) {
    extern __shared__ int cur[];
    int t = threadIdx.x;
    long row = (long)blockIdx.x * nb;
    for (int i = t; i < nb; i += 256) cur[i] = bucketStart[i] + basemat[row + i];
    __syncthreads();
    int base = blockIdx.x * ECHUNK + t;
#pragma unroll
    for (int k = 0; k < 8; ++k) {
        int i = base + k * 256;
        if (i < e) {
            int d = dst[i];
            int b = d >> BSHIFT;
            int pos = atomicAdd(&cur[b], 1);               // LDS atomic, block-private
            ebuf[pos] = ((unsigned)(d & (BNODES - 1)) << 25) | (unsigned)src[i];
        }
    }
}

// ---- pass 5: one block per bucket -> dst-ordered CSR slice, dinv, graph ranges ----
__global__ void fill2_k(const unsigned int* __restrict__ ebuf,
                        const int* __restrict__ bucketStart,
                        const int* __restrict__ batch, float* __restrict__ dinv,
                        int* __restrict__ start, int* __restrict__ csr,
                        int* __restrict__ gstart, int* __restrict__ gend, int n) {
    __shared__ int scnt[BNODES], sincl[BNODES], scur[BNODES];
    int t = threadIdx.x;
    int b = blockIdx.x;
    int node0 = b << BSHIFT;
    int nNodes = min(BNODES, n - node0);
    if (t < BNODES) scnt[t] = 0;
    int e0 = bucketStart[b], e1 = bucketStart[b + 1];
    __syncthreads();
    for (int i = e0 + t; i < e1; i += 256)
        atomicAdd(&scnt[ebuf[i] >> 25], 1);
    __syncthreads();
    int val = (t < BNODES) ? scnt[t] : 0;
    if (t < BNODES) sincl[t] = val;
    __syncthreads();
    for (int off = 1; off < BNODES; off <<= 1) {
        int tmp = (t >= off && t < BNODES) ? sincl[t - off] : 0;
        __syncthreads();
        if (t < BNODES) sincl[t] += tmp;
        __syncthreads();
    }
    if (t < nNodes) {
        int v = node0 + t;
        int st = e0 + sincl[t] - val;     // exclusive within bucket
        start[v] = st;
        scur[t] = st;
        dinv[v] = rsqrtf((float)(val + 1));
        int g = batch[v];                 // sorted-batch boundary detection
        if (v == 0 || batch[v - 1] != g) gstart[g] = v;
        if (v == n - 1 || batch[v + 1] != g) gend[g] = v + 1;
    }
    __syncthreads();
    for (int i = e0 + t; i < e1; i += 256) {
        unsigned rec = ebuf[i];
        int pos = atomicAdd(&scur[rec >> 25], 1);
        csr[pos] = (int)(rec & 0x1FFFFFFu);   // scatter within L2-local 8 KB slice
    }
}

// ---- dense GEMM (f32 A)  C[n,64](bf16 pairs) = scale[row] * (A @ W) ----
// 64x64 tile/block; thread (rg,cg) computes rows 4rg..+3, cols 4cg..+3.
__global__ void gemm_k(const float* __restrict__ A, const float* __restrict__ W,
                       const float* __restrict__ scale,
                       unsigned long long* __restrict__ C, int n) {
    __shared__ float4 Wl4[64 * 16];   // 16 KB: W[k][4c..4c+3]
    __shared__ float4 Xl4[64 * 16];   // 16 KB: X[r][4k..4k+3]
    int t = threadIdx.x;
    const float4* W4 = (const float4*)W;
#pragma unroll
    for (int i = 0; i < 4; ++i) Wl4[t + 256 * i] = W4[t + 256 * i];
    const float4* A4 = (const float4*)A;
    long fbase = (long)blockIdx.x * 1024;
    long fmax  = (long)n * 16;
#pragma unroll
    for (int i = 0; i < 4; ++i) {
        long f = fbase + t + 256 * i;
        float4 v;
        if (f < fmax) v = A4[f];
        else { v.x = 0.f; v.y = 0.f; v.z = 0.f; v.w = 0.f; }
        Xl4[t + 256 * i] = v;
    }
    __syncthreads();
    int rg = t >> 4, cg = t & 15;
    float a00 = 0.f, a01 = 0.f, a02 = 0.f, a03 = 0.f;
    float a10 = 0.f, a11 = 0.f, a12 = 0.f, a13 = 0.f;
    float a20 = 0.f, a21 = 0.f, a22 = 0.f, a23 = 0.f;
    float a30 = 0.f, a31 = 0.f, a32 = 0.f, a33 = 0.f;
#pragma unroll 4
    for (int k4 = 0; k4 < 16; ++k4) {
        float4 w0 = Wl4[(4 * k4 + 0) * 16 + cg];
        float4 w1 = Wl4[(4 * k4 + 1) * 16 + cg];
        float4 w2 = Wl4[(4 * k4 + 2) * 16 + cg];
        float4 w3 = Wl4[(4 * k4 + 3) * 16 + cg];
        float4 x0 = Xl4[(4 * rg + 0) * 16 + k4];
        float4 x1 = Xl4[(4 * rg + 1) * 16 + k4];
        float4 x2 = Xl4[(4 * rg + 2) * 16 + k4];
        float4 x3 = Xl4[(4 * rg + 3) * 16 + k4];
        a00 += x0.x * w0.x + x0.y * w1.x + x0.z * w2.x + x0.w * w3.x;
        a01 += x0.x * w0.y + x0.y * w1.y + x0.z * w2.y + x0.w * w3.y;
        a02 += x0.x * w0.z + x0.y * w1.z + x0.z * w2.z + x0.w * w3.z;
        a03 += x0.x * w0.w + x0.y * w1.w + x0.z * w2.w + x0.w * w3.w;
        a10 += x1.x * w0.x + x1.y * w1.x + x1.z * w2.x + x1.w * w3.x;
        a11 += x1.x * w0.y + x1.y * w1.y + x1.z * w2.y + x1.w * w3.y;
        a12 += x1.x * w0.z + x1.y * w1.z + x1.z * w2.z + x1.w * w3.z;
        a13 += x1.x * w0.w + x1.y * w1.w + x1.z * w2.w + x1.w * w3.w;
        a20 += x2.x * w0.x + x2.y * w1.x + x2.z * w2.x + x2.w * w3.x;
        a21 += x2.x * w0.y + x2.y * w1.y + x2.z * w2.y + x2.w * w3.y;
        a22 += x2.x * w0.z + x2.y * w1.z + x2.z * w2.z + x2.w * w3.z;
        a23 += x2.x * w0.w + x2.y * w1.w + x2.z * w2.w + x2.w * w3.w;
        a30 += x3.x * w0.x + x3.y * w1.x + x3.z * w2.x + x3.w * w3.x;
        a31 += x3.x * w0.y + x3.y * w1.y + x3.z * w2.y + x3.w * w3.y;
        a32 += x3.x * w0.z + x3.y * w1.z + x3.z * w2.z + x3.w * w3.z;
        a33 += x3.x * w0.w + x3.y * w1.w + x3.z * w2.w + x3.w * w3.w;
    }
    int vb = blockIdx.x * 64 + rg * 4;
    int v;
    float s;
    unsigned long long u;
    v = vb + 0;
    if (v < n) {
        s = scale[v];
        u  = (unsigned long long)(((unsigned int)f32_to_bf16(s * a01) << 16) | (unsigned int)f32_to_bf16(s * a00));
        u |= (unsigned long long)(((unsigned int)f32_to_bf16(s * a03) << 16) | (unsigned int)f32_to_bf16(s * a02)) << 32;
        C[(long)v * 16 + cg] = u;
    }
    v = vb + 1;
    if (v < n) {
        s = scale[v];
        u  = (unsigned long long)(((unsigned int)f32_to_bf16(s * a11) << 16) | (unsigned int)f32_to_bf16(s * a10));
        u |= (unsigned long long)(((unsigned int)f32_to_bf16(s * a13) << 16) | (unsigned int)f32_to_bf16(s * a12)) << 32;
        C[(long)v * 16 + cg] = u;
    }
    v = vb + 2;
    if (v < n) {
        s = scale[v];
        u  = (unsigned long long)(((unsigned int)f32_to_bf16(s * a21) << 16) | (unsigned int)f32_to_bf16(s * a20));
        u |= (unsigned long long)(((unsigned int)f32_to_bf16(s * a23) << 16) | (unsigned int)f32_to_bf16(s * a22)) << 32;
        C[(long)v * 16 + cg] = u;
    }
    v = vb + 3;
    if (v < n) {
        s = scale[v];
        u  = (unsigned long long)(((unsigned int)f32_to_bf16(s * a31) << 16) | (unsigned int)f32_to_bf16(s * a30));
        u |= (unsigned long long)(((unsigned int)f32_to_bf16(s * a33) << 16) | (unsigned int)f32_to_bf16(s * a32)) << 32;
        C[(long)v * 16 + cg] = u;
    }
}

// ---- dense GEMM (bf16 A)  same structure; A staged bf16->f32 in LDS ----
__global__ void gemmb_k(const unsigned long long* __restrict__ A8, const float* __restrict__ W,
                        const float* __restrict__ scale,
                        unsigned long long* __restrict__ C, int n) {
    __shared__ float4 Wl4[64 * 16];
    __shared__ float4 Xl4[64 * 16];
    int t = threadIdx.x;
    const float4* W4 = (const float4*)W;
#pragma unroll
    for (int i = 0; i < 4; ++i) Wl4[t + 256 * i] = W4[t + 256 * i];
    long ubase = (long)blockIdx.x * 1024;   // ull units (8 B = 4 bf16)
    long umax  = (long)n * 16;
#pragma unroll
    for (int i = 0; i < 4; ++i) {
        long f = ubase + t + 256 * i;
        unsigned long long u = (f < umax) ? A8[f] : 0ull;
        float4 v;
        v.x = __uint_as_float((unsigned int)(u & 0xFFFFu) << 16);
        v.y = __uint_as_float((unsigned int)u & 0xFFFF0000u);
        v.z = __uint_as_float((unsigned int)((u >> 32) & 0xFFFFu) << 16);
        v.w = __uint_as_float((unsigned int)(u >> 48) << 16);
        Xl4[t + 256 * i] = v;
    }
    __syncthreads();
    int rg = t >> 4, cg = t & 15;
    float a00 = 0.f, a01 = 0.f, a02 = 0.f, a03 = 0.f;
    float a10 = 0.f, a11 = 0.f, a12 = 0.f, a13 = 0.f;
    float a20 = 0.f, a21 = 0.f, a22 = 0.f, a23 = 0.f;
    float a30 = 0.f, a31 = 0.f, a32 = 0.f, a33 = 0.f;
#pragma unroll 4
    for (int k4 = 0; k4 < 16; ++k4) {
        float4 w0 = Wl4[(4 * k4 + 0) * 16 + cg];
        float4 w1 = Wl4[(4 * k4 + 1) * 16 + cg];
        float4 w2 = Wl4[(4 * k4 + 2) * 16 + cg];
        float4 w3 = Wl4[(4 * k4 + 3) * 16 + cg];
        float4 x0 = Xl4[(4 * rg + 0) * 16 + k4];
        float4 x1 = Xl4[(4 * rg + 1) * 16 + k4];
        float4 x2 = Xl4[(4 * rg + 2) * 16 + k4];
        float4 x3 = Xl4[(4 * rg + 3) * 16 + k4];
        a00 += x0.x * w0.x + x0.y * w1.x + x0.z * w2.x + x0.w * w3.x;
        a01 += x0.x * w0.y + x0.y * w1.y + x0.z * w2.y + x0.w * w3.y;
        a02 += x0.x * w0.z + x0.y * w1.z + x0.z * w2.z + x0.w * w3.z;
        a03 += x0.x * w0.w + x0.y * w1.w + x0.z * w2.w + x0.w * w3.w;
        a10 += x1.x * w0.x + x1.y * w1.x + x1.z * w2.x + x1.w * w3.x;
        a11 += x1.x * w0.y + x1.y * w1.y + x1.z * w2.y + x1.w * w3.y;
        a12 += x1.x * w0.z + x1.y * w1.z + x1.z * w2.z + x1.w * w3.z;
        a13 += x1.x * w0.w + x1.y * w1.w + x1.z * w2.w + x1.w * w3.w;
        a20 += x2.x * w0.x + x2.y * w1.x + x2.z * w2.x + x2.w * w3.x;
        a21 += x2.x * w0.y + x2.y * w1.y + x2.z * w2.y + x2.w * w3.y;
        a22 += x2.x * w0.z + x2.y * w1.z + x2.z * w2.z + x2.w * w3.z;
        a23 += x2.x * w0.w + x2.y * w1.w + x2.z * w2.w + x2.w * w3.w;
        a30 += x3.x * w0.x + x3.y * w1.x + x3.z * w2.x + x3.w * w3.x;
        a31 += x3.x * w0.y + x3.y * w1.y + x3.z * w2.y + x3.w * w3.y;
        a32 += x3.x * w0.z + x3.y * w1.z + x3.z * w2.z + x3.w * w3.z;
        a33 += x3.x * w0.w + x3.y * w1.w + x3.z * w2.w + x3.w * w3.w;
    }
    int vb = blockIdx.x * 64 + rg * 4;
    int v;
    float s;
    unsigned long long u;
    v = vb + 0;
    if (v < n) {
        s = scale[v];
        u  = (unsigned long long)(((unsigned int)f32_to_bf16(s * a01) << 16) | (unsigned int)f32_to_bf16(s * a00));
        u |= (unsigned long long)(((unsigned int)f32_to_bf16(s * a03) << 16) | (unsigned int)f32_to_bf16(s * a02)) << 32;
        C[(long)v * 16 + cg] = u;
    }
    v = vb + 1;
    if (v < n) {
        s = scale[v];
        u  = (unsigned long long)(((unsigned int)f32_to_bf16(s * a11) << 16) | (unsigned int)f32_to_bf16(s * a10));
        u |= (unsigned long long)(((unsigned int)f32_to_bf16(s * a13) << 16) | (unsigned int)f32_to_bf16(s * a12)) << 32;
        C[(long)v * 16 + cg] = u;
    }
    v = vb + 2;
    if (v < n) {
        s = scale[v];
        u  = (unsigned long long)(((unsigned int)f32_to_bf16(s * a21) << 16) | (unsigned int)f32_to_bf16(s * a20));
        u |= (unsigned long long)(((unsigned int)f32_to_bf16(s * a23) << 16) | (unsigned int)f32_to_bf16(s * a22)) << 32;
        C[(long)v * 16 + cg] = u;
    }
    v = vb + 3;
    if (v < n) {
        s = scale[v];
        u  = (unsigned long long)(((unsigned int)f32_to_bf16(s * a31) << 16) | (unsigned int)f32_to_bf16(s * a30));
        u |= (unsigned long long)(((unsigned int)f32_to_bf16(s * a33) << 16) | (unsigned int)f32_to_bf16(s * a32)) << 32;
        C[(long)v * 16 + cg] = u;
    }
}

// ---- gather core (R17-proven): half-wave per row, dword/lane, 8 in flight ----
// lane covers dim pair p=lane&31 via dword (2 bf16); half-wave h=lane>>5
// handles edges i+h. Returns value for dim d = 2p+h (self-loop included).
__device__ __forceinline__ float gather_row(const unsigned int* __restrict__ xp,
                                            const int* __restrict__ csr,
                                            int s0, int d0, int h, int p, int v) {
    float l0 = 0.f, l1 = 0.f, l2 = 0.f, l3 = 0.f;
    float h0 = 0.f, h1 = 0.f, h2 = 0.f, h3 = 0.f;
    int i = 0;
    for (; i + 16 <= d0; i += 16) {       // 8 gathers in flight
        int j0 = csr[s0 + i +  0 + h];
        int j1 = csr[s0 + i +  2 + h];
        int j2 = csr[s0 + i +  4 + h];
        int j3 = csr[s0 + i +  6 + h];
        int j4 = csr[s0 + i +  8 + h];
        int j5 = csr[s0 + i + 10 + h];
        int j6 = csr[s0 + i + 12 + h];
        int j7 = csr[s0 + i + 14 + h];
        unsigned int u0 = xp[(long)j0 * 32 + p];
        unsigned int u1 = xp[(long)j1 * 32 + p];
        unsigned int u2 = xp[(long)j2 * 32 + p];
        unsigned int u3 = xp[(long)j3 * 32 + p];
        unsigned int u4 = xp[(long)j4 * 32 + p];
        unsigned int u5 = xp[(long)j5 * 32 + p];
        unsigned int u6 = xp[(long)j6 * 32 + p];
        unsigned int u7 = xp[(long)j7 * 32 + p];
        l0 += __uint_as_float(u0 << 16);  h0 += __uint_as_float(u0 & 0xFFFF0000u);
        l1 += __uint_as_float(u1 << 16);  h1 += __uint_as_float(u1 & 0xFFFF0000u);
        l2 += __uint_as_float(u2 << 16);  h2 += __uint_as_float(u2 & 0xFFFF0000u);
        l3 += __uint_as_float(u3 << 16);  h3 += __uint_as_float(u3 & 0xFFFF0000u);
        l0 += __uint_as_float(u4 << 16);  h0 += __uint_as_float(u4 & 0xFFFF0000u);
        l1 += __uint_as_float(u5 << 16);  h1 += __uint_as_float(u5 & 0xFFFF0000u);
        l2 += __uint_as_float(u6 << 16);  h2 += __uint_as_float(u6 & 0xFFFF0000u);
        l3 += __uint_as_float(u7 << 16);  h3 += __uint_as_float(u7 & 0xFFFF0000u);
    }
    for (; i + 8 <= d0; i += 8) {         // 4 gathers in flight
        int j0 = csr[s0 + i + 0 + h];
        int j1 = csr[s0 + i + 2 + h];
        int j2 = csr[s0 + i + 4 + h];
        int j3 = csr[s0 + i + 6 + h];
        unsigned int u0 = xp[(long)j0 * 32 + p];
        unsigned int u1 = xp[(long)j1 * 32 + p];
        unsigned int u2 = xp[(long)j2 * 32 + p];
        unsigned int u3 = xp[(long)j3 * 32 + p];
        l0 += __uint_as_float(u0 << 16);  h0 += __uint_as_float(u0 & 0xFFFF0000u);
        l1 += __uint_as_float(u1 << 16);  h1 += __uint_as_float(u1 & 0xFFFF0000u);
        l2 += __uint_as_float(u2 << 16);  h2 += __uint_as_float(u2 & 0xFFFF0000u);
        l3 += __uint_as_float(u3 << 16);  h3 += __uint_as_float(u3 & 0xFFFF0000u);
    }
    for (; i + 4 <= d0; i += 4) {         // 2 gathers in flight
        int j0 = csr[s0 + i + 0 + h];
        int j1 = csr[s0 + i + 2 + h];
        unsigned int u0 = xp[(long)j0 * 32 + p];
        unsigned int u1 = xp[(long)j1 * 32 + p];
        l0 += __uint_as_float(u0 << 16);  h0 += __uint_as_float(u0 & 0xFFFF0000u);
        l1 += __uint_as_float(u1 << 16);  h1 += __uint_as_float(u1 & 0xFFFF0000u);
    }
    for (; i + 2 <= d0; i += 2) {
        int j = csr[s0 + i + h];
        unsigned int u = xp[(long)j * 32 + p];
        l0 += __uint_as_float(u << 16);
        h0 += __uint_as_float(u & 0xFFFF0000u);
    }
    if (i < d0 && h == 0) {               // odd leftover edge: half-wave 0 only
        int j = csr[s0 + i];
        unsigned int u = xp[(long)j * 32 + p];
        l0 += __uint_as_float(u << 16);
        h0 += __uint_as_float(u & 0xFFFF0000u);
    }
    float al = (l0 + l1) + (l2 + l3);
    float ah = (h0 + h1) + (h2 + h3);
    al += __shfl_xor(al, 32);             // merge the two half-waves
    ah += __shfl_xor(ah, 32);
    unsigned int us = xp[(long)v * 32 + p];   // self loop
    al += __uint_as_float(us << 16);
    ah += __uint_as_float(us & 0xFFFF0000u);
    return h ? ah : al;
}

// ---- aggregation (layer 1): h1 = relu(dinv*gather + b1), stored bf16 pairs ----
__global__ void agg_k(const unsigned int* __restrict__ xp, const float* __restrict__ dinv,
                      const int* __restrict__ start, const int* __restrict__ csr,
                      const float* __restrict__ bias, unsigned int* __restrict__ hb, int n) {
    int t = threadIdx.x;
    int lane = t & 63;
    int h = lane >> 5;
    int p = lane & 31;
    int v = blockIdx.x * 4 + (t >> 6);
    if (v >= n) return;
    int s0 = start[v];
    int d0 = start[v + 1] - s0;
    float sum = gather_row(xp, csr, s0, d0, h, p, v);
    int d = 2 * p + h;
    float val = fmaxf(sum * dinv[v] + bias[d], 0.f);
    float other = __shfl_xor(val, 32);    // partner holds dim 2p+1 (or 2p)
    if (h == 0) {                         // lanes 0..31 store 128 B contiguous
        unsigned int u = ((unsigned int)f32_to_bf16(other) << 16) | (unsigned int)f32_to_bf16(val);
        hb[(long)v * 32 + p] = u;         // dword store: lo=dim 2p, hi=dim 2p+1
    }
}

// ---- aggpool: chunk=4 nodes/wave, 32x replicated pooled accumulator ----
__global__ void aggpool_k(const unsigned int* __restrict__ xp, const float* __restrict__ dinv,
                          const int* __restrict__ start, const int* __restrict__ csr,
                          const float* __restrict__ b2, const int* __restrict__ batch,
                          float* __restrict__ pooledR, int n) {
    int t = threadIdx.x;
    int lane = t & 63;
    int h = lane >> 5, p = lane & 31;
    int wid = blockIdx.x * 4 + (t >> 6);
    int v0 = wid * 4;
    if (v0 >= n) return;
    int v1 = min(v0 + 4, n);
    int d = 2 * p + h;
    float bias = b2[d];
    long rbase = (long)(wid & (NREP - 1)) * (NGRAPH * NDIM);   // replica slice
    int gcur = -1;
    float acc = 0.f;
    for (int v = v0; v < v1; ++v) {                // one gather context at a time
        int g = batch[v];                          // wave-uniform broadcast load
        if (g != gcur) {
            if (gcur >= 0) atomicAdd(&pooledR[rbase + gcur * NDIM + d], acc);
            gcur = g;
            acc = 0.f;
        }
        int s0 = start[v];
        int d0 = start[v + 1] - s0;
        float sum = gather_row(xp, csr, s0, d0, h, p, v);
        acc += fmaxf(sum * dinv[v] + bias, 0.f);
    }
    if (gcur >= 0) atomicAdd(&pooledR[rbase + gcur * NDIM + d], acc);
}

// ---- head (folds the 32 pooled replicas inline) ----
__global__ void final_k(const float* __restrict__ pooledR, const int* __restrict__ gstart,
                        const int* __restrict__ gend,
                        const float* __restrict__ Wlin, const float* __restrict__ blin,
                        float* __restrict__ out, int nclass) {
    int t = blockIdx.x * blockDim.x + threadIdx.x;
    if (t >= NGRAPH * nclass) return;
    int g = t / nclass, c = t % nclass;
    float cnt = (float)(gend[g] - gstart[g]);
    float inv = 1.f / fmaxf(cnt, 1.f);
    float acc = 0.f;
    for (int j = 0; j < NDIM; ++j) {
        float pj = 0.f;
        for (int r = 0; r < NREP; ++r) pj += pooledR[(long)r * (NGRAPH * NDIM) + g * NDIM + j];
        acc += pj * Wlin[j * nclass + c];
    }
    out[t] = acc * inv + blin[c];
}

extern "C" void kernel_launch(void* const* d_in, const int* in_sizes, int n_in,
                              void* d_out, int out_size, void* d_ws, size_t ws_size,
                              hipStream_t stream) {
    const float* x     = (const float*)d_in[0];
    const int*   ei    = (const int*)d_in[1];
    const int*   batch = (const int*)d_in[2];
    const float* W1    = (const float*)d_in[3];
    const float* b1    = (const float*)d_in[4];
    const float* W2    = (const float*)d_in[5];
    const float* b2    = (const float*)d_in[6];
    const float* Wlin  = (const float*)d_in[7];
    const float* blin  = (const float*)d_in[8];
    float* out = (float*)d_out;

    const int N = in_sizes[0] / NDIM;        // 100000
    const int E = in_sizes[1] / 2;           // 1600000
    const int NCLASS = in_sizes[7] / NDIM;   // 10
    const int* src = ei;
    const int* dst = ei + E;
    const int NB   = (N + BNODES - 1) >> BSHIFT;        // 782 buckets (<=1024)
    const int NBLK = (E + ECHUNK - 1) / ECHUNK;         // 782 edge blocks (<=1024)

    // ---- workspace carve-out (each 256B-aligned) ----
    size_t o = 0;
    char* wsp = (char*)d_ws;
    auto take = [&](size_t nbytes) -> void* {
        void* p = (void*)(wsp + o);
        o += (nbytes + 255) & ~(size_t)255;
        return p;
    };
    int*   gstart    = (int*)take(NGRAPH * 4);
    int*   gend      = (int*)take(NGRAPH * 4);
    float* pooledR   = (float*)take((size_t)NREP * NGRAPH * NDIM * 4);   // 512 KB
    size_t zero_bytes = o;                    // everything above must start at 0
    int*   cntmat   = (int*)take((size_t)NBLK * NB * 4);
    int*   basemat  = (int*)take((size_t)NBLK * NB * 4);
    int*   bucketTot   = (int*)take((size_t)NB * 4);
    int*   bucketStart = (int*)take((size_t)(NB + 1) * 4);
    float* dinv  = (float*)take((size_t)N * 4);
    int*   start = (int*)take((size_t)(N + 1) * 4);
    int*   csr   = (int*)take((size_t)E * 4);
    unsigned int* ebuf = (unsigned int*)take((size_t)E * 4);
    unsigned int* xws  = (unsigned int*)take((size_t)N * NDIM * 2);   // bf16 pairs
    unsigned int* hb   = (unsigned int*)take((size_t)N * NDIM * 2);   // h1 bf16 pairs
    (void)ws_size;

    hipMemsetAsync(d_ws, 0, zero_bytes, stream);

    int rbl = (N + 3) / 4;                    // 4 nodes per block (agg)
    int gbl = (N + 63) / 64;                  // 64 rows per block (gemm)
    int pbl = (N + 15) / 16;                  // aggpool: 4 waves x 4 nodes per block

    // CSR build (deterministic two-pass binning, zero global atomics)
    bincnt_k<<<NBLK, 256, (size_t)NB * 4, stream>>>(dst, cntmat, E, NB);
    colscan_k<<<NB, 1024, 0, stream>>>(cntmat, basemat, bucketTot, NBLK, NB);
    bscan_k<<<1, 1024, 0, stream>>>(bucketTot, bucketStart, start, NB, N, E);
    bscatter_k<<<NBLK, 256, (size_t)NB * 4, stream>>>(src, dst, bucketStart, basemat, ebuf, E, NB);
    fill2_k<<<NB, 256, 0, stream>>>(ebuf, bucketStart, batch, dinv, start, csr, gstart, gend, N);

    // layer 1
    gemm_k<<<gbl, 256, 0, stream>>>(x, W1, dinv, (unsigned long long*)xws, N);
    agg_k<<<rbl, 256, 0, stream>>>(xws, dinv, start, csr, b1, hb, N);
    // layer 2 (bf16 A)
    gemmb_k<<<gbl, 256, 0, stream>>>((const unsigned long long*)hb, W2, dinv, (unsigned long long*)xws, N);
    // fused layer2-agg + replicated register mean-pool
    aggpool_k<<<pbl, 256, 0, stream>>>(xws, dinv, start, csr, b2, batch, pooledR, N);
    // head (replica fold inline)
    final_k<<<(NGRAPH * NCLASS + 255) / 256, 256, 0, stream>>>(pooledR, gstart, gend, Wlin, blin, out, NCLASS);
}

// Round 20
// 282.069 us; speedup vs baseline: 1.3674x; 1.3674x over previous
//
#include <hip/hip_runtime.h>
#include <hip/hip_bf16.h>

// GCN: h1 = relu(Â (x W1) + b1); h2 = relu(Â (h1 W2) + b2);
// out = mean_pool(h2, batch) @ Wlin + blin,  Â = D^-1/2 (A+I) D^-1/2
//
// R5/R6: bucketed CSR build, deterministic two-pass, zero global atomics.
// R8/R9 LESSON: sub-dword per-lane global stores defeat L2 write-merge.
// R10/R17/R18 LESSON: gather bound by outstanding-miss slots per lane;
//     R17 half-wave core (dword/lane, 8 in flight) is the optimum.
// R12 LESSON: multi-NODE gather unroll spills. One node context per wave.
// R14 LESSON: same-address atomic chains ~125 ns/link; keep <= ~100.
// R15/R16: replicated pooled accumulators (32x) decouple chains from occupancy.
// R19: CSR build x4 parallelism (ECHUNK 2048, NBLK 782); h stored bf16.
// R19 LESSON: folding the 32x replica fold into 640-thread final_k made it
//     110 us (2048 scattered loads/thread @ 0.1% occupancy). Wide separate
//     reduce_k costs ~2 us. NEVER put O(K) loops in tiny-grid kernels.
// R20: restore separate reduce_k; final_k reads folded pooled. Rest = R19.

#define NDIM 64
#define NGRAPH 64
#define NREP 32
#define BSHIFT 7                      // 128 nodes per bucket
#define BNODES 128
#define ECHUNK 2048                   // edges per block in bincnt/bscatter (8/thread)

__device__ __forceinline__ unsigned short f32_to_bf16(float f) {
    unsigned int u = __float_as_uint(f);
    unsigned int r = 0x7FFFu + ((u >> 16) & 1u);   // round-to-nearest-even
    return (unsigned short)((u + r) >> 16);
}

// ---- pass 1: per-(block,bucket) edge counts via LDS histogram ----
__global__ void bincnt_k(const int* __restrict__ dst, int* __restrict__ cntmat,
                         int e, int nb) {
    extern __shared__ int hist[];
    int t = threadIdx.x;
    for (int i = t; i < nb; i += 256) hist[i] = 0;
    __syncthreads();
    int base = blockIdx.x * ECHUNK + t;
#pragma unroll
    for (int k = 0; k < 8; ++k) {
        int i = base + k * 256;
        if (i < e) atomicAdd(&hist[dst[i] >> BSHIFT], 1);   // LDS atomic
    }
    __syncthreads();
    long row = (long)blockIdx.x * nb;
    for (int i = t; i < nb; i += 256) cntmat[row + i] = hist[i];
}

// ---- pass 2: per-bucket exclusive scan across blocks (one block per bucket) ----
// 1024 threads: supports nblk <= 1024
__global__ void colscan_k(const int* __restrict__ cntmat, int* __restrict__ basemat,
                          int* __restrict__ bucketTot, int nblk, int nb) {
    __shared__ int s[1024];
    int b = blockIdx.x;
    int t = threadIdx.x;
    int v = (t < nblk) ? cntmat[(long)t * nb + b] : 0;
    s[t] = v;
    __syncthreads();
    for (int off = 1; off < 1024; off <<= 1) {
        int tmp = (t >= off) ? s[t - off] : 0;
        __syncthreads();
        s[t] += tmp;
        __syncthreads();
    }
    if (t < nblk) basemat[(long)t * nb + b] = s[t] - v;   // exclusive within column
    if (t == 1023) bucketTot[b] = s[1023];
}

// ---- pass 3: exclusive scan of bucket totals (single block, nb<=1024) ----
__global__ void bscan_k(const int* __restrict__ bucketTot, int* __restrict__ bucketStart,
                        int* __restrict__ start, int nb, int n, int e) {
    __shared__ int s[1024];
    int t = threadIdx.x;
    int v = (t < nb) ? bucketTot[t] : 0;
    s[t] = v;
    __syncthreads();
    for (int off = 1; off < 1024; off <<= 1) {
        int tmp = (t >= off) ? s[t - off] : 0;
        __syncthreads();
        s[t] += tmp;
        __syncthreads();
    }
    if (t < nb) bucketStart[t + 1] = s[t];
    if (t == 0) { bucketStart[0] = 0; start[n] = e; }   // CSR sentinel
}

// ---- pass 4: scatter packed (dst_local<<25 | src) via block-private LDS cursors ----
__global__ void bscatter_k(const int* __restrict__ src, const int* __restrict__ dst,
                           const int* __restrict__ bucketStart,
                           const int* __restrict__ basemat,
                           unsigned int* __restrict__ ebuf, int e, int nb) {
    extern __shared__ int cur[];
    int t = threadIdx.x;
    long row = (long)blockIdx.x * nb;
    for (int i = t; i < nb; i += 256) cur[i] = bucketStart[i] + basemat[row + i];
    __syncthreads();
    int base = blockIdx.x * ECHUNK + t;
#pragma unroll
    for (int k = 0; k < 8; ++k) {
        int i = base + k * 256;
        if (i < e) {
            int d = dst[i];
            int b = d >> BSHIFT;
            int pos = atomicAdd(&cur[b], 1);               // LDS atomic, block-private
            ebuf[pos] = ((unsigned)(d & (BNODES - 1)) << 25) | (unsigned)src[i];
        }
    }
}

// ---- pass 5: one block per bucket -> dst-ordered CSR slice, dinv, graph ranges ----
__global__ void fill2_k(const unsigned int* __restrict__ ebuf,
                        const int* __restrict__ bucketStart,
                        const int* __restrict__ batch, float* __restrict__ dinv,
                        int* __restrict__ start, int* __restrict__ csr,
                        int* __restrict__ gstart, int* __restrict__ gend, int n) {
    __shared__ int scnt[BNODES], sincl[BNODES], scur[BNODES];
    int t = threadIdx.x;
    int b = blockIdx.x;
    int node0 = b << BSHIFT;
    int nNodes = min(BNODES, n - node0);
    if (t < BNODES) scnt[t] = 0;
    int e0 = bucketStart[b], e1 = bucketStart[b + 1];
    __syncthreads();
    for (int i = e0 + t; i < e1; i += 256)
        atomicAdd(&scnt[ebuf[i] >> 25], 1);
    __syncthreads();
    int val = (t < BNODES) ? scnt[t] : 0;
    if (t < BNODES) sincl[t] = val;
    __syncthreads();
    for (int off = 1; off < BNODES; off <<= 1) {
        int tmp = (t >= off && t < BNODES) ? sincl[t - off] : 0;
        __syncthreads();
        if (t < BNODES) sincl[t] += tmp;
        __syncthreads();
    }
    if (t < nNodes) {
        int v = node0 + t;
        int st = e0 + sincl[t] - val;     // exclusive within bucket
        start[v] = st;
        scur[t] = st;
        dinv[v] = rsqrtf((float)(val + 1));
        int g = batch[v];                 // sorted-batch boundary detection
        if (v == 0 || batch[v - 1] != g) gstart[g] = v;
        if (v == n - 1 || batch[v + 1] != g) gend[g] = v + 1;
    }
    __syncthreads();
    for (int i = e0 + t; i < e1; i += 256) {
        unsigned rec = ebuf[i];
        int pos = atomicAdd(&scur[rec >> 25], 1);
        csr[pos] = (int)(rec & 0x1FFFFFFu);   // scatter within L2-local 8 KB slice
    }
}

// ---- dense GEMM (f32 A)  C[n,64](bf16 pairs) = scale[row] * (A @ W) ----
__global__ void gemm_k(const float* __restrict__ A, const float* __restrict__ W,
                       const float* __restrict__ scale,
                       unsigned long long* __restrict__ C, int n) {
    __shared__ float4 Wl4[64 * 16];   // 16 KB: W[k][4c..4c+3]
    __shared__ float4 Xl4[64 * 16];   // 16 KB: X[r][4k..4k+3]
    int t = threadIdx.x;
    const float4* W4 = (const float4*)W;
#pragma unroll
    for (int i = 0; i < 4; ++i) Wl4[t + 256 * i] = W4[t + 256 * i];
    const float4* A4 = (const float4*)A;
    long fbase = (long)blockIdx.x * 1024;
    long fmax  = (long)n * 16;
#pragma unroll
    for (int i = 0; i < 4; ++i) {
        long f = fbase + t + 256 * i;
        float4 v;
        if (f < fmax) v = A4[f];
        else { v.x = 0.f; v.y = 0.f; v.z = 0.f; v.w = 0.f; }
        Xl4[t + 256 * i] = v;
    }
    __syncthreads();
    int rg = t >> 4, cg = t & 15;
    float a00 = 0.f, a01 = 0.f, a02 = 0.f, a03 = 0.f;
    float a10 = 0.f, a11 = 0.f, a12 = 0.f, a13 = 0.f;
    float a20 = 0.f, a21 = 0.f, a22 = 0.f, a23 = 0.f;
    float a30 = 0.f, a31 = 0.f, a32 = 0.f, a33 = 0.f;
#pragma unroll 4
    for (int k4 = 0; k4 < 16; ++k4) {
        float4 w0 = Wl4[(4 * k4 + 0) * 16 + cg];
        float4 w1 = Wl4[(4 * k4 + 1) * 16 + cg];
        float4 w2 = Wl4[(4 * k4 + 2) * 16 + cg];
        float4 w3 = Wl4[(4 * k4 + 3) * 16 + cg];
        float4 x0 = Xl4[(4 * rg + 0) * 16 + k4];
        float4 x1 = Xl4[(4 * rg + 1) * 16 + k4];
        float4 x2 = Xl4[(4 * rg + 2) * 16 + k4];
        float4 x3 = Xl4[(4 * rg + 3) * 16 + k4];
        a00 += x0.x * w0.x + x0.y * w1.x + x0.z * w2.x + x0.w * w3.x;
        a01 += x0.x * w0.y + x0.y * w1.y + x0.z * w2.y + x0.w * w3.y;
        a02 += x0.x * w0.z + x0.y * w1.z + x0.z * w2.z + x0.w * w3.z;
        a03 += x0.x * w0.w + x0.y * w1.w + x0.z * w2.w + x0.w * w3.w;
        a10 += x1.x * w0.x + x1.y * w1.x + x1.z * w2.x + x1.w * w3.x;
        a11 += x1.x * w0.y + x1.y * w1.y + x1.z * w2.y + x1.w * w3.y;
        a12 += x1.x * w0.z + x1.y * w1.z + x1.z * w2.z + x1.w * w3.z;
        a13 += x1.x * w0.w + x1.y * w1.w + x1.z * w2.w + x1.w * w3.w;
        a20 += x2.x * w0.x + x2.y * w1.x + x2.z * w2.x + x2.w * w3.x;
        a21 += x2.x * w0.y + x2.y * w1.y + x2.z * w2.y + x2.w * w3.y;
        a22 += x2.x * w0.z + x2.y * w1.z + x2.z * w2.z + x2.w * w3.z;
        a23 += x2.x * w0.w + x2.y * w1.w + x2.z * w2.w + x2.w * w3.w;
        a30 += x3.x * w0.x + x3.y * w1.x + x3.z * w2.x + x3.w * w3.x;
        a31 += x3.x * w0.y + x3.y * w1.y + x3.z * w2.y + x3.w * w3.y;
        a32 += x3.x * w0.z + x3.y * w1.z + x3.z * w2.z + x3.w * w3.z;
        a33 += x3.x * w0.w + x3.y * w1.w + x3.z * w2.w + x3.w * w3.w;
    }
    int vb = blockIdx.x * 64 + rg * 4;
    int v;
    float s;
    unsigned long long u;
    v = vb + 0;
    if (v < n) {
        s = scale[v];
        u  = (unsigned long long)(((unsigned int)f32_to_bf16(s * a01) << 16) | (unsigned int)f32_to_bf16(s * a00));
        u |= (unsigned long long)(((unsigned int)f32_to_bf16(s * a03) << 16) | (unsigned int)f32_to_bf16(s * a02)) << 32;
        C[(long)v * 16 + cg] = u;
    }
    v = vb + 1;
    if (v < n) {
        s = scale[v];
        u  = (unsigned long long)(((unsigned int)f32_to_bf16(s * a11) << 16) | (unsigned int)f32_to_bf16(s * a10));
        u |= (unsigned long long)(((unsigned int)f32_to_bf16(s * a13) << 16) | (unsigned int)f32_to_bf16(s * a12)) << 32;
        C[(long)v * 16 + cg] = u;
    }
    v = vb + 2;
    if (v < n) {
        s = scale[v];
        u  = (unsigned long long)(((unsigned int)f32_to_bf16(s * a21) << 16) | (unsigned int)f32_to_bf16(s * a20));
        u |= (unsigned long long)(((unsigned int)f32_to_bf16(s * a23) << 16) | (unsigned int)f32_to_bf16(s * a22)) << 32;
        C[(long)v * 16 + cg] = u;
    }
    v = vb + 3;
    if (v < n) {
        s = scale[v];
        u  = (unsigned long long)(((unsigned int)f32_to_bf16(s * a31) << 16) | (unsigned int)f32_to_bf16(s * a30));
        u |= (unsigned long long)(((unsigned int)f32_to_bf16(s * a33) << 16) | (unsigned int)f32_to_bf16(s * a32)) << 32;
        C[(long)v * 16 + cg] = u;
    }
}

// ---- dense GEMM (bf16 A)  same structure; A staged bf16->f32 in LDS ----
__global__ void gemmb_k(const unsigned long long* __restrict__ A8, const float* __restrict__ W,
                        const float* __restrict__ scale,
                        unsigned long long* __restrict__ C, int n) {
    __shared__ float4 Wl4[64 * 16];
    __shared__ float4 Xl4[64 * 16];
    int t = threadIdx.x;
    const float4* W4 = (const float4*)W;
#pragma unroll
    for (int i = 0; i < 4; ++i) Wl4[t + 256 * i] = W4[t + 256 * i];
    long ubase = (long)blockIdx.x * 1024;   // ull units (8 B = 4 bf16)
    long umax  = (long)n * 16;
#pragma unroll
    for (int i = 0; i < 4; ++i) {
        long f = ubase + t + 256 * i;
        unsigned long long u = (f < umax) ? A8[f] : 0ull;
        float4 v;
        v.x = __uint_as_float((unsigned int)(u & 0xFFFFu) << 16);
        v.y = __uint_as_float((unsigned int)u & 0xFFFF0000u);
        v.z = __uint_as_float((unsigned int)((u >> 32) & 0xFFFFu) << 16);
        v.w = __uint_as_float((unsigned int)(u >> 48) << 16);
        Xl4[t + 256 * i] = v;
    }
    __syncthreads();
    int rg = t >> 4, cg = t & 15;
    float a00 = 0.f, a01 = 0.f, a02 = 0.f, a03 = 0.f;
    float a10 = 0.f, a11 = 0.f, a12 = 0.f, a13 = 0.f;
    float a20 = 0.f, a21 = 0.f, a22 = 0.f, a23 = 0.f;
    float a30 = 0.f, a31 = 0.f, a32 = 0.f, a33 = 0.f;
#pragma unroll 4
    for (int k4 = 0; k4 < 16; ++k4) {
        float4 w0 = Wl4[(4 * k4 + 0) * 16 + cg];
        float4 w1 = Wl4[(4 * k4 + 1) * 16 + cg];
        float4 w2 = Wl4[(4 * k4 + 2) * 16 + cg];
        float4 w3 = Wl4[(4 * k4 + 3) * 16 + cg];
        float4 x0 = Xl4[(4 * rg + 0) * 16 + k4];
        float4 x1 = Xl4[(4 * rg + 1) * 16 + k4];
        float4 x2 = Xl4[(4 * rg + 2) * 16 + k4];
        float4 x3 = Xl4[(4 * rg + 3) * 16 + k4];
        a00 += x0.x * w0.x + x0.y * w1.x + x0.z * w2.x + x0.w * w3.x;
        a01 += x0.x * w0.y + x0.y * w1.y + x0.z * w2.y + x0.w * w3.y;
        a02 += x0.x * w0.z + x0.y * w1.z + x0.z * w2.z + x0.w * w3.z;
        a03 += x0.x * w0.w + x0.y * w1.w + x0.z * w2.w + x0.w * w3.w;
        a10 += x1.x * w0.x + x1.y * w1.x + x1.z * w2.x + x1.w * w3.x;
        a11 += x1.x * w0.y + x1.y * w1.y + x1.z * w2.y + x1.w * w3.y;
        a12 += x1.x * w0.z + x1.y * w1.z + x1.z * w2.z + x1.w * w3.z;
        a13 += x1.x * w0.w + x1.y * w1.w + x1.z * w2.w + x1.w * w3.w;
        a20 += x2.x * w0.x + x2.y * w1.x + x2.z * w2.x + x2.w * w3.x;
        a21 += x2.x * w0.y + x2.y * w1.y + x2.z * w2.y + x2.w * w3.y;
        a22 += x2.x * w0.z + x2.y * w1.z + x2.z * w2.z + x2.w * w3.z;
        a23 += x2.x * w0.w + x2.y * w1.w + x2.z * w2.w + x2.w * w3.w;
        a30 += x3.x * w0.x + x3.y * w1.x + x3.z * w2.x + x3.w * w3.x;
        a31 += x3.x * w0.y + x3.y * w1.y + x3.z * w2.y + x3.w * w3.y;
        a32 += x3.x * w0.z + x3.y * w1.z + x3.z * w2.z + x3.w * w3.z;
        a33 += x3.x * w0.w + x3.y * w1.w + x3.z * w2.w + x3.w * w3.w;
    }
    int vb = blockIdx.x * 64 + rg * 4;
    int v;
    float s;
    unsigned long long u;
    v = vb + 0;
    if (v < n) {
        s = scale[v];
        u  = (unsigned long long)(((unsigned int)f32_to_bf16(s * a01) << 16) | (unsigned int)f32_to_bf16(s * a00));
        u |= (unsigned long long)(((unsigned int)f32_to_bf16(s * a03) << 16) | (unsigned int)f32_to_bf16(s * a02)) << 32;
        C[(long)v * 16 + cg] = u;
    }
    v = vb + 1;
    if (v < n) {
        s = scale[v];
        u  = (unsigned long long)(((unsigned int)f32_to_bf16(s * a11) << 16) | (unsigned int)f32_to_bf16(s * a10));
        u |= (unsigned long long)(((unsigned int)f32_to_bf16(s * a13) << 16) | (unsigned int)f32_to_bf16(s * a12)) << 32;
        C[(long)v * 16 + cg] = u;
    }
    v = vb + 2;
    if (v < n) {
        s = scale[v];
        u  = (unsigned long long)(((unsigned int)f32_to_bf16(s * a21) << 16) | (unsigned int)f32_to_bf16(s * a20));
        u |= (unsigned long long)(((unsigned int)f32_to_bf16(s * a23) << 16) | (unsigned int)f32_to_bf16(s * a22)) << 32;
        C[(long)v * 16 + cg] = u;
    }
    v = vb + 3;
    if (v < n) {
        s = scale[v];
        u  = (unsigned long long)(((unsigned int)f32_to_bf16(s * a31) << 16) | (unsigned int)f32_to_bf16(s * a30));
        u |= (unsigned long long)(((unsigned int)f32_to_bf16(s * a33) << 16) | (unsigned int)f32_to_bf16(s * a32)) << 32;
        C[(long)v * 16 + cg] = u;
    }
}

// ---- gather core (R17-proven): half-wave per row, dword/lane, 8 in flight ----
__device__ __forceinline__ float gather_row(const unsigned int* __restrict__ xp,
                                            const int* __restrict__ csr,
                                            int s0, int d0, int h, int p, int v) {
    float l0 = 0.f, l1 = 0.f, l2 = 0.f, l3 = 0.f;
    float h0 = 0.f, h1 = 0.f, h2 = 0.f, h3 = 0.f;
    int i = 0;
    for (; i + 16 <= d0; i += 16) {       // 8 gathers in flight
        int j0 = csr[s0 + i +  0 + h];
        int j1 = csr[s0 + i +  2 + h];
        int j2 = csr[s0 + i +  4 + h];
        int j3 = csr[s0 + i +  6 + h];
        int j4 = csr[s0 + i +  8 + h];
        int j5 = csr[s0 + i + 10 + h];
        int j6 = csr[s0 + i + 12 + h];
        int j7 = csr[s0 + i + 14 + h];
        unsigned int u0 = xp[(long)j0 * 32 + p];
        unsigned int u1 = xp[(long)j1 * 32 + p];
        unsigned int u2 = xp[(long)j2 * 32 + p];
        unsigned int u3 = xp[(long)j3 * 32 + p];
        unsigned int u4 = xp[(long)j4 * 32 + p];
        unsigned int u5 = xp[(long)j5 * 32 + p];
        unsigned int u6 = xp[(long)j6 * 32 + p];
        unsigned int u7 = xp[(long)j7 * 32 + p];
        l0 += __uint_as_float(u0 << 16);  h0 += __uint_as_float(u0 & 0xFFFF0000u);
        l1 += __uint_as_float(u1 << 16);  h1 += __uint_as_float(u1 & 0xFFFF0000u);
        l2 += __uint_as_float(u2 << 16);  h2 += __uint_as_float(u2 & 0xFFFF0000u);
        l3 += __uint_as_float(u3 << 16);  h3 += __uint_as_float(u3 & 0xFFFF0000u);
        l0 += __uint_as_float(u4 << 16);  h0 += __uint_as_float(u4 & 0xFFFF0000u);
        l1 += __uint_as_float(u5 << 16);  h1 += __uint_as_float(u5 & 0xFFFF0000u);
        l2 += __uint_as_float(u6 << 16);  h2 += __uint_as_float(u6 & 0xFFFF0000u);
        l3 += __uint_as_float(u7 << 16);  h3 += __uint_as_float(u7 & 0xFFFF0000u);
    }
    for (; i + 8 <= d0; i += 8) {         // 4 gathers in flight
        int j0 = csr[s0 + i + 0 + h];
        int j1 = csr[s0 + i + 2 + h];
        int j2 = csr[s0 + i + 4 + h];
        int j3 = csr[s0 + i + 6 + h];
        unsigned int u0 = xp[(long)j0 * 32 + p];
        unsigned int u1 = xp[(long)j1 * 32 + p];
        unsigned int u2 = xp[(long)j2 * 32 + p];
        unsigned int u3 = xp[(long)j3 * 32 + p];
        l0 += __uint_as_float(u0 << 16);  h0 += __uint_as_float(u0 & 0xFFFF0000u);
        l1 += __uint_as_float(u1 << 16);  h1 += __uint_as_float(u1 & 0xFFFF0000u);
        l2 += __uint_as_float(u2 << 16);  h2 += __uint_as_float(u2 & 0xFFFF0000u);
        l3 += __uint_as_float(u3 << 16);  h3 += __uint_as_float(u3 & 0xFFFF0000u);
    }
    for (; i + 4 <= d0; i += 4) {         // 2 gathers in flight
        int j0 = csr[s0 + i + 0 + h];
        int j1 = csr[s0 + i + 2 + h];
        unsigned int u0 = xp[(long)j0 * 32 + p];
        unsigned int u1 = xp[(long)j1 * 32 + p];
        l0 += __uint_as_float(u0 << 16);  h0 += __uint_as_float(u0 & 0xFFFF0000u);
        l1 += __uint_as_float(u1 << 16);  h1 += __uint_as_float(u1 & 0xFFFF0000u);
    }
    for (; i + 2 <= d0; i += 2) {
        int j = csr[s0 + i + h];
        unsigned int u = xp[(long)j * 32 + p];
        l0 += __uint_as_float(u << 16);
        h0 += __uint_as_float(u & 0xFFFF0000u);
    }
    if (i < d0 && h == 0) {               // odd leftover edge: half-wave 0 only
        int j = csr[s0 + i];
        unsigned int u = xp[(long)j * 32 + p];
        l0 += __uint_as_float(u << 16);
        h0 += __uint_as_float(u & 0xFFFF0000u);
    }
    float al = (l0 + l1) + (l2 + l3);
    float ah = (h0 + h1) + (h2 + h3);
    al += __shfl_xor(al, 32);             // merge the two half-waves
    ah += __shfl_xor(ah, 32);
    unsigned int us = xp[(long)v * 32 + p];   // self loop
    al += __uint_as_float(us << 16);
    ah += __uint_as_float(us & 0xFFFF0000u);
    return h ? ah : al;
}

// ---- aggregation (layer 1): h1 = relu(dinv*gather + b1), stored bf16 pairs ----
__global__ void agg_k(const unsigned int* __restrict__ xp, const float* __restrict__ dinv,
                      const int* __restrict__ start, const int* __restrict__ csr,
                      const float* __restrict__ bias, unsigned int* __restrict__ hb, int n) {
    int t = threadIdx.x;
    int lane = t & 63;
    int h = lane >> 5;
    int p = lane & 31;
    int v = blockIdx.x * 4 + (t >> 6);
    if (v >= n) return;
    int s0 = start[v];
    int d0 = start[v + 1] - s0;
    float sum = gather_row(xp, csr, s0, d0, h, p, v);
    int d = 2 * p + h;
    float val = fmaxf(sum * dinv[v] + bias[d], 0.f);
    float other = __shfl_xor(val, 32);    // partner holds dim 2p+1 (or 2p)
    if (h == 0) {                         // lanes 0..31 store 128 B contiguous
        unsigned int u = ((unsigned int)f32_to_bf16(other) << 16) | (unsigned int)f32_to_bf16(val);
        hb[(long)v * 32 + p] = u;         // dword store: lo=dim 2p, hi=dim 2p+1
    }
}

// ---- aggpool: chunk=4 nodes/wave, 32x replicated pooled accumulator ----
__global__ void aggpool_k(const unsigned int* __restrict__ xp, const float* __restrict__ dinv,
                          const int* __restrict__ start, const int* __restrict__ csr,
                          const float* __restrict__ b2, const int* __restrict__ batch,
                          float* __restrict__ pooledR, int n) {
    int t = threadIdx.x;
    int lane = t & 63;
    int h = lane >> 5, p = lane & 31;
    int wid = blockIdx.x * 4 + (t >> 6);
    int v0 = wid * 4;
    if (v0 >= n) return;
    int v1 = min(v0 + 4, n);
    int d = 2 * p + h;
    float bias = b2[d];
    long rbase = (long)(wid & (NREP - 1)) * (NGRAPH * NDIM);   // replica slice
    int gcur = -1;
    float acc = 0.f;
    for (int v = v0; v < v1; ++v) {                // one gather context at a time
        int g = batch[v];                          // wave-uniform broadcast load
        if (g != gcur) {
            if (gcur >= 0) atomicAdd(&pooledR[rbase + gcur * NDIM + d], acc);
            gcur = g;
            acc = 0.f;
        }
        int s0 = start[v];
        int d0 = start[v + 1] - s0;
        float sum = gather_row(xp, csr, s0, d0, h, p, v);
        acc += fmaxf(sum * dinv[v] + bias, 0.f);
    }
    if (gcur >= 0) atomicAdd(&pooledR[rbase + gcur * NDIM + d], acc);
}

// ---- fold the 32 pooled replicas (wide: 4096 threads, coalesced) ----
__global__ void reduce_k(const float* __restrict__ pooledR, float* __restrict__ pooled) {
    int t = blockIdx.x * 256 + threadIdx.x;
    if (t >= NGRAPH * NDIM) return;
    float s = 0.f;
    for (int r = 0; r < NREP; ++r) s += pooledR[(long)r * (NGRAPH * NDIM) + t];
    pooled[t] = s;
}

// ---- head: out[g,c] = (pooled[g,:]/max(cnt,1)) @ Wlin + blin ----
__global__ void final_k(const float* __restrict__ pooled, const int* __restrict__ gstart,
                        const int* __restrict__ gend,
                        const float* __restrict__ Wlin, const float* __restrict__ blin,
                        float* __restrict__ out, int nclass) {
    int t = blockIdx.x * blockDim.x + threadIdx.x;
    if (t >= NGRAPH * nclass) return;
    int g = t / nclass, c = t % nclass;
    float cnt = (float)(gend[g] - gstart[g]);
    float inv = 1.f / fmaxf(cnt, 1.f);
    float acc = 0.f;
    for (int j = 0; j < NDIM; ++j) acc += pooled[g * NDIM + j] * Wlin[j * nclass + c];
    out[t] = acc * inv + blin[c];
}

extern "C" void kernel_launch(void* const* d_in, const int* in_sizes, int n_in,
                              void* d_out, int out_size, void* d_ws, size_t ws_size,
                              hipStream_t stream) {
    const float* x     = (const float*)d_in[0];
    const int*   ei    = (const int*)d_in[1];
    const int*   batch = (const int*)d_in[2];
    const float* W1    = (const float*)d_in[3];
    const float* b1    = (const float*)d_in[4];
    const float* W2    = (const float*)d_in[5];
    const float* b2    = (const float*)d_in[6];
    const float* Wlin  = (const float*)d_in[7];
    const float* blin  = (const float*)d_in[8];
    float* out = (float*)d_out;

    const int N = in_sizes[0] / NDIM;        // 100000
    const int E = in_sizes[1] / 2;           // 1600000
    const int NCLASS = in_sizes[7] / NDIM;   // 10
    const int* src = ei;
    const int* dst = ei + E;
    const int NB   = (N + BNODES - 1) >> BSHIFT;        // 782 buckets (<=1024)
    const int NBLK = (E + ECHUNK - 1) / ECHUNK;         // 782 edge blocks (<=1024)

    // ---- workspace carve-out (each 256B-aligned) ----
    size_t o = 0;
    char* wsp = (char*)d_ws;
    auto take = [&](size_t nbytes) -> void* {
        void* p = (void*)(wsp + o);
        o += (nbytes + 255) & ~(size_t)255;
        return p;
    };
    int*   gstart    = (int*)take(NGRAPH * 4);
    int*   gend      = (int*)take(NGRAPH * 4);
    float* pooledR   = (float*)take((size_t)NREP * NGRAPH * NDIM * 4);   // 512 KB
    size_t zero_bytes = o;                    // everything above must start at 0
    float* pooled    = (float*)take(NGRAPH * NDIM * 4);
    int*   cntmat   = (int*)take((size_t)NBLK * NB * 4);
    int*   basemat  = (int*)take((size_t)NBLK * NB * 4);
    int*   bucketTot   = (int*)take((size_t)NB * 4);
    int*   bucketStart = (int*)take((size_t)(NB + 1) * 4);
    float* dinv  = (float*)take((size_t)N * 4);
    int*   start = (int*)take((size_t)(N + 1) * 4);
    int*   csr   = (int*)take((size_t)E * 4);
    unsigned int* ebuf = (unsigned int*)take((size_t)E * 4);
    unsigned int* xws  = (unsigned int*)take((size_t)N * NDIM * 2);   // bf16 pairs
    unsigned int* hb   = (unsigned int*)take((size_t)N * NDIM * 2);   // h1 bf16 pairs
    (void)ws_size;

    hipMemsetAsync(d_ws, 0, zero_bytes, stream);

    int rbl = (N + 3) / 4;                    // 4 nodes per block (agg)
    int gbl = (N + 63) / 64;                  // 64 rows per block (gemm)
    int pbl = (N + 15) / 16;                  // aggpool: 4 waves x 4 nodes per block

    // CSR build (deterministic two-pass binning, zero global atomics)
    bincnt_k<<<NBLK, 256, (size_t)NB * 4, stream>>>(dst, cntmat, E, NB);
    colscan_k<<<NB, 1024, 0, stream>>>(cntmat, basemat, bucketTot, NBLK, NB);
    bscan_k<<<1, 1024, 0, stream>>>(bucketTot, bucketStart, start, NB, N, E);
    bscatter_k<<<NBLK, 256, (size_t)NB * 4, stream>>>(src, dst, bucketStart, basemat, ebuf, E, NB);
    fill2_k<<<NB, 256, 0, stream>>>(ebuf, bucketStart, batch, dinv, start, csr, gstart, gend, N);

    // layer 1
    gemm_k<<<gbl, 256, 0, stream>>>(x, W1, dinv, (unsigned long long*)xws, N);
    agg_k<<<rbl, 256, 0, stream>>>(xws, dinv, start, csr, b1, hb, N);
    // layer 2 (bf16 A)
    gemmb_k<<<gbl, 256, 0, stream>>>((const unsigned long long*)hb, W2, dinv, (unsigned long long*)xws, N);
    // fused layer2-agg + replicated register mean-pool
    aggpool_k<<<pbl, 256, 0, stream>>>(xws, dinv, start, csr, b2, batch, pooledR, N);
    reduce_k<<<(NGRAPH * NDIM + 255) / 256, 256, 0, stream>>>(pooledR, pooled);
    // head
    final_k<<<(NGRAPH * NCLASS + 255) / 256, 256, 0, stream>>>(pooled, gstart, gend, Wlin, blin, out, NCLASS);
}